// Round 9
// baseline (372.824 us; speedup 1.0000x reference)
//
#include <hip/hip_runtime.h>
#include <hip/hip_fp16.h>
#include <cmath>

#define D 64
#define PA_EDGES 4096     // edges per partition/bhist block
#define BSHIFT 7          // bucket = 128 nodes
#define BNODES 128
#define MAXBUCK 1024      // supports N <= 131072
#define PB_CAP 4096       // LDS csr staging per bucket (avg 2048, ~45 sigma)

// ---------------------------------------------------------------------------
// Per-BUCKET histogram, LDS-privatized. Each block pre-aggregates 4096 edges
// in LDS, flushes <=nbuck aggregated atomics (replaces 1.6M random atomics).
// ---------------------------------------------------------------------------
__global__ __launch_bounds__(256)
void bhist_kernel(const int* __restrict__ dst, int* __restrict__ bcnt, int E, int nbuck) {
    __shared__ int lh[MAXBUCK];
    const int t = threadIdx.x;
    const int e0 = blockIdx.x * PA_EDGES;
    const int ecnt = min(PA_EDGES, E - e0);
    for (int i = t; i < MAXBUCK; i += 256) lh[i] = 0;
    __syncthreads();
    for (int i = t; i < ecnt; i += 256) atomicAdd(&lh[dst[e0 + i] >> BSHIFT], 1);
    __syncthreads();
    for (int b = t; b < nbuck; b += 256) {
        const int c = lh[b];
        if (c) atomicAdd(&bcnt[b], c);
    }
}

// ---------------------------------------------------------------------------
// Exclusive scan of bucket counts -> bbase (and cursor copy). One block.
// ---------------------------------------------------------------------------
__global__ __launch_bounds__(256)
void bucket_scan_kernel(const int* __restrict__ bcnt, int* __restrict__ bbase,
                        int* __restrict__ cursor, int nbuck, int E) {
    __shared__ int red[256];
    const int t = threadIdx.x;
    const int c0 = (4 * t + 0 < nbuck) ? bcnt[4 * t + 0] : 0;
    const int c1 = (4 * t + 1 < nbuck) ? bcnt[4 * t + 1] : 0;
    const int c2 = (4 * t + 2 < nbuck) ? bcnt[4 * t + 2] : 0;
    const int c3 = (4 * t + 3 < nbuck) ? bcnt[4 * t + 3] : 0;
    red[t] = c0 + c1 + c2 + c3;
    __syncthreads();
    for (int off = 1; off < 256; off <<= 1) {
        int u = (t >= off) ? red[t - off] : 0;
        __syncthreads();
        red[t] += u;
        __syncthreads();
    }
    const int excl = (t == 0) ? 0 : red[t - 1];
    const int e0 = excl, e1 = excl + c0, e2 = excl + c0 + c1, e3 = excl + c0 + c1 + c2;
    if (4 * t + 0 <= nbuck) { bbase[4 * t + 0] = e0; }
    if (4 * t + 1 <= nbuck) { bbase[4 * t + 1] = e1; }
    if (4 * t + 2 <= nbuck) { bbase[4 * t + 2] = e2; }
    if (4 * t + 3 <= nbuck) { bbase[4 * t + 3] = e3; }
    if (4 * t + 0 < nbuck) cursor[4 * t + 0] = e0;
    if (4 * t + 1 < nbuck) cursor[4 * t + 1] = e1;
    if (4 * t + 2 < nbuck) cursor[4 * t + 2] = e2;
    if (4 * t + 3 < nbuck) cursor[4 * t + 3] = e3;
    if (t == 255) bbase[nbuck] = E;   // total (exclusive scan end)
}

// ---------------------------------------------------------------------------
// Bucket partition: (src, dst) -> packed 32-bit (src<<7 | dst&127), grouped
// by bucket (dst>>7) in `pairs`. LDS-staged; int LDS atomics only (native
// ds_add_u32 -- float LDS atomics are CAS loops on HIP, never use them).
// ---------------------------------------------------------------------------
__global__ __launch_bounds__(256)
void partition_kernel(const int* __restrict__ src, const int* __restrict__ dst,
                      int* __restrict__ cursor, unsigned* __restrict__ pairs,
                      int E, int nbuck) {
    __shared__ int lhist[MAXBUCK];            // counts, then local fill cursors
    __shared__ int lbase[MAXBUCK];            // local exclusive scan
    __shared__ int gbase[MAXBUCK];            // reserved global positions
    __shared__ int red[256];
    __shared__ unsigned stage[PA_EDGES];      // 16 KB
    __shared__ unsigned short sbuck[PA_EDGES];// 8 KB bucket id per staged slot

    const int t = threadIdx.x;
    const int e0 = blockIdx.x * PA_EDGES;
    const int ecnt = min(PA_EDGES, E - e0);

    for (int i = t; i < MAXBUCK; i += 256) lhist[i] = 0;
    __syncthreads();
    for (int i = t; i < ecnt; i += 256) atomicAdd(&lhist[dst[e0 + i] >> BSHIFT], 1);
    __syncthreads();

    // exclusive scan over 1024 entries: each thread owns 4 consecutive slots
    const int c0 = lhist[4 * t], c1 = lhist[4 * t + 1];
    const int c2 = lhist[4 * t + 2], c3 = lhist[4 * t + 3];
    red[t] = c0 + c1 + c2 + c3;
    __syncthreads();
    for (int off = 1; off < 256; off <<= 1) {
        int u = (t >= off) ? red[t - off] : 0;
        __syncthreads();
        red[t] += u;
        __syncthreads();
    }
    const int excl = (t == 0) ? 0 : red[t - 1];
    lbase[4 * t]     = excl;
    lbase[4 * t + 1] = excl + c0;
    lbase[4 * t + 2] = excl + c0 + c1;
    lbase[4 * t + 3] = excl + c0 + c1 + c2;
    for (int b = t; b < nbuck; b += 256) {
        const int c = lhist[b];
        gbase[b] = c ? atomicAdd(&cursor[b], c) : 0;
    }
    __syncthreads();
    for (int i = t; i < MAXBUCK; i += 256) lhist[i] = 0;   // reuse as fill cursors
    __syncthreads();
    for (int i = t; i < ecnt; i += 256) {
        const int d = dst[e0 + i];
        const int b = d >> BSHIFT;
        const int p = lbase[b] + atomicAdd(&lhist[b], 1);
        stage[p] = ((unsigned)src[e0 + i] << BSHIFT) | (unsigned)(d & (BNODES - 1));
        sbuck[p] = (unsigned short)b;
    }
    __syncthreads();
    for (int i = t; i < ecnt; i += 256) {
        const int b = sbuck[i];
        pairs[gbase[b] + (i - lbase[b])] = stage[i];
    }
}

// ---------------------------------------------------------------------------
// Bucket CSR fill + per-node rowStart derivation, fully on-chip.
// ---------------------------------------------------------------------------
__global__ __launch_bounds__(256)
void bucket_fill_kernel(const unsigned* __restrict__ pairs, const int* __restrict__ bbase,
                        int* __restrict__ rowStart, int* __restrict__ csr, int n, int E) {
    __shared__ int lcsr[PB_CAP];          // 16 KB
    __shared__ int lcnt[BNODES];          // per-node degree
    __shared__ int lrs[BNODES];           // per-node row start (bucket-relative)
    __shared__ int s[BNODES];             // scan workspace
    __shared__ int lfill[BNODES];
    const int t = threadIdx.x;
    const int node0 = blockIdx.x << BSHIFT;
    const int bn = min(BNODES, n - node0);
    const int base = bbase[blockIdx.x];
    const int cntE = bbase[blockIdx.x + 1] - base;

    if (t < BNODES) { lcnt[t] = 0; lfill[t] = 0; }
    __syncthreads();
    for (int i = t; i < cntE; i += 256)
        atomicAdd(&lcnt[pairs[base + i] & (BNODES - 1)], 1);
    __syncthreads();
    if (t < BNODES) s[t] = lcnt[t];
    __syncthreads();
    for (int off = 1; off < BNODES; off <<= 1) {
        int u = (t >= off && t < BNODES) ? s[t - off] : 0;
        __syncthreads();
        if (t < BNODES) s[t] += u;
        __syncthreads();
    }
    if (t < BNODES) lrs[t] = (t == 0) ? 0 : s[t - 1];
    __syncthreads();
    if (t < bn) rowStart[node0 + t] = base + lrs[t];
    if (blockIdx.x == gridDim.x - 1 && t == 0) rowStart[n] = E;

    if (cntE <= PB_CAP) {
        for (int i = t; i < cntE; i += 256) {
            const unsigned pr = pairs[base + i];
            const int dl = (int)(pr & (BNODES - 1));
            const int p = lrs[dl] + atomicAdd(&lfill[dl], 1);
            lcsr[p] = (int)(pr >> BSHIFT);
        }
        __syncthreads();
        for (int i = t; i < cntE; i += 256) csr[base + i] = lcsr[i];
    } else {   // safety fallback (statistically unreachable for random dst)
        for (int i = t; i < cntE; i += 256) {
            const unsigned pr = pairs[base + i];
            const int dl = (int)(pr & (BNODES - 1));
            const int p = base + lrs[dl] + atomicAdd(&lfill[dl], 1);
            csr[p] = (int)(pr >> BSHIFT);
        }
    }
}

// ---------------------------------------------------------------------------
// f32 -> f16 cast (vectorized, grid-stride).
// ---------------------------------------------------------------------------
__global__ __launch_bounds__(256)
void cast_half_kernel(const float* __restrict__ in, __half* __restrict__ out, int n2) {
    const float2* in2 = (const float2*)in;
    __half2* out2 = (__half2*)out;
    int i = blockIdx.x * 256 + threadIdx.x;
    const int st = gridDim.x * 256;
    for (; i < n2; i += st) {
        const float2 v = in2[i];
        out2[i] = __floats2half2_rn(v.x, v.y);
    }
}

// ---------------------------------------------------------------------------
// Gather-mean from an fp16 feature copy: m[node] = mean(xh[nbrs(node)]).
// One wave per node; lane-group g (16 lanes) loads one neighbor row (128 B)
// via 8 B dwordx2 -> 4 rows in flight per gather batch. f32 accumulation.
// ---------------------------------------------------------------------------
__device__ __forceinline__ void addh4(float4& a, const __half* __restrict__ p) {
    union { unsigned long long u; __half2 h[2]; } r;
    r.u = *(const unsigned long long*)p;       // 8 B load
    const float2 f0 = __half22float2(r.h[0]);
    const float2 f1 = __half22float2(r.h[1]);
    a.x += f0.x; a.y += f0.y; a.z += f1.x; a.w += f1.y;
}

__global__ __launch_bounds__(256)
void aggmean_kernel(const __half* __restrict__ xh, const int* __restrict__ rowStart,
                    const int* __restrict__ csr, float* __restrict__ m, int n) {
    const int lane = threadIdx.x & 63;
    const int g = lane >> 4;              // group 0..3
    const int gl = lane & 15;             // lane in group
    const int wave = threadIdx.x >> 6;
    const int gw = blockIdx.x * 4 + wave;
    const int nw = gridDim.x * 4;

    for (int node = gw; node < n; node += nw) {
        const int r0 = rowStart[node];
        const int r1 = rowStart[node + 1];
        float4 acc0 = make_float4(0.f, 0.f, 0.f, 0.f);
        float4 acc1 = make_float4(0.f, 0.f, 0.f, 0.f);

        int j = r0;
        for (; j + 16 <= r1; j += 16) {
            const int i0 = csr[j + 0  + g];
            const int i1 = csr[j + 4  + g];
            const int i2 = csr[j + 8  + g];
            const int i3 = csr[j + 12 + g];
            addh4(acc0, &xh[(size_t)i0 * D + gl * 4]);
            addh4(acc1, &xh[(size_t)i1 * D + gl * 4]);
            addh4(acc0, &xh[(size_t)i2 * D + gl * 4]);
            addh4(acc1, &xh[(size_t)i3 * D + gl * 4]);
        }
        const int rem = r1 - j;
        if (rem > 0) {
            if (0 + g < rem) {
                const int sidx = csr[j + 0 + g];
                addh4(acc0, &xh[(size_t)sidx * D + gl * 4]);
            }
            if (4 + g < rem) {
                const int sidx = csr[j + 4 + g];
                addh4(acc1, &xh[(size_t)sidx * D + gl * 4]);
            }
            if (8 + g < rem) {
                const int sidx = csr[j + 8 + g];
                addh4(acc0, &xh[(size_t)sidx * D + gl * 4]);
            }
            if (12 + g < rem) {
                const int sidx = csr[j + 12 + g];
                addh4(acc1, &xh[(size_t)sidx * D + gl * 4]);
            }
        }

        float4 a;
        a.x = acc0.x + acc1.x; a.y = acc0.y + acc1.y;
        a.z = acc0.z + acc1.z; a.w = acc0.w + acc1.w;
        a.x += __shfl_xor(a.x, 16); a.y += __shfl_xor(a.y, 16);
        a.z += __shfl_xor(a.z, 16); a.w += __shfl_xor(a.w, 16);
        a.x += __shfl_xor(a.x, 32); a.y += __shfl_xor(a.y, 32);
        a.z += __shfl_xor(a.z, 32); a.w += __shfl_xor(a.w, 32);

        if (lane < 16) {
            const float rdeg = 1.0f / fmaxf((float)(r1 - r0), 1.0f);
            float4 o = make_float4(a.x * rdeg, a.y * rdeg, a.z * rdeg, a.w * rdeg);
            *(float4*)&m[(size_t)node * D + gl * 4] = o;
        }
    }
}

// ---------------------------------------------------------------------------
// Fused SAGE transform, NODE-UNROLL-4: h = ELU(m@Wa + ba + x@Wb) for 4 nodes
// per wave iteration. Rounds 6-8 proved hipcc will NOT keep 128 weight VGPRs
// resident (remat/spill at VGPR=72 regardless of launch bounds, waves_per_eu
// attrs, or asm pins). So amortize instead: each rematerialized L1-hit
// weight load now feeds FMAs for FOUR nodes -> VMEM issue per node drops
// ~4x (the round-6 bottleneck), while 4 independent accumulator chains
// saturate the VALU pipe. Register need stays low, so the allocator's
// occupancy greed is harmless.
// ---------------------------------------------------------------------------
__device__ __forceinline__ float rl(unsigned v, int k) {
    return __uint_as_float(__builtin_amdgcn_readlane(v, k));
}

__global__ __launch_bounds__(256)
void fused_mm_kernel(const float* __restrict__ m,
                     const float* __restrict__ xres,
                     const float* __restrict__ Wa,
                     const float* __restrict__ ba,
                     const float* __restrict__ Wb,
                     float* __restrict__ out,
                     __half* __restrict__ hout,   // nullable
                     int n) {
    const int lane = threadIdx.x & 63;
    const int wave = threadIdx.x >> 6;
    const int gw = blockIdx.x * 4 + wave;
    const int nw = gridDim.x * 4;
    const float bva = ba[lane];

    for (int base = gw * 4; base < n; base += nw * 4) {
        const int n0 = base, n1 = base + 1, n2 = base + 2, n3 = base + 3;
        const bool v1 = n1 < n, v2 = n2 < n, v3 = n3 < n;

        const unsigned mu0 = __float_as_uint(m[(size_t)n0 * D + lane]);
        const unsigned xu0 = __float_as_uint(xres[(size_t)n0 * D + lane]);
        const unsigned mu1 = v1 ? __float_as_uint(m[(size_t)n1 * D + lane]) : 0u;
        const unsigned xu1 = v1 ? __float_as_uint(xres[(size_t)n1 * D + lane]) : 0u;
        const unsigned mu2 = v2 ? __float_as_uint(m[(size_t)n2 * D + lane]) : 0u;
        const unsigned xu2 = v2 ? __float_as_uint(xres[(size_t)n2 * D + lane]) : 0u;
        const unsigned mu3 = v3 ? __float_as_uint(m[(size_t)n3 * D + lane]) : 0u;
        const unsigned xu3 = v3 ? __float_as_uint(xres[(size_t)n3 * D + lane]) : 0u;

        float oA0 = bva, oB0 = 0.0f;
        float oA1 = bva, oB1 = 0.0f;
        float oA2 = bva, oB2 = 0.0f;
        float oA3 = bva, oB3 = 0.0f;

#pragma unroll
        for (int k = 0; k < D; k += 2) {
            const float wa0 = Wa[(k + 0) * D + lane];
            const float wa1 = Wa[(k + 1) * D + lane];
            const float wb0 = Wb[(k + 0) * D + lane];
            const float wb1 = Wb[(k + 1) * D + lane];

            oA0 = fmaf(rl(mu0, k), wa0, oA0); oA0 = fmaf(rl(xu0, k), wb0, oA0);
            oB0 = fmaf(rl(mu0, k + 1), wa1, oB0); oB0 = fmaf(rl(xu0, k + 1), wb1, oB0);
            oA1 = fmaf(rl(mu1, k), wa0, oA1); oA1 = fmaf(rl(xu1, k), wb0, oA1);
            oB1 = fmaf(rl(mu1, k + 1), wa1, oB1); oB1 = fmaf(rl(xu1, k + 1), wb1, oB1);
            oA2 = fmaf(rl(mu2, k), wa0, oA2); oA2 = fmaf(rl(xu2, k), wb0, oA2);
            oB2 = fmaf(rl(mu2, k + 1), wa1, oB2); oB2 = fmaf(rl(xu2, k + 1), wb1, oB2);
            oA3 = fmaf(rl(mu3, k), wa0, oA3); oA3 = fmaf(rl(xu3, k), wb0, oA3);
            oB3 = fmaf(rl(mu3, k + 1), wa1, oB3); oB3 = fmaf(rl(xu3, k + 1), wb1, oB3);
        }

        float h0 = oA0 + oB0;
        float h1 = oA1 + oB1;
        float h2 = oA2 + oB2;
        float h3 = oA3 + oB3;
        h0 = h0 > 0.0f ? h0 : expm1f(h0);
        h1 = h1 > 0.0f ? h1 : expm1f(h1);
        h2 = h2 > 0.0f ? h2 : expm1f(h2);
        h3 = h3 > 0.0f ? h3 : expm1f(h3);

        out[(size_t)n0 * D + lane] = h0;
        if (v1) out[(size_t)n1 * D + lane] = h1;
        if (v2) out[(size_t)n2 * D + lane] = h2;
        if (v3) out[(size_t)n3 * D + lane] = h3;
        if (hout) {
            hout[(size_t)n0 * D + lane] = __float2half_rn(h0);
            if (v1) hout[(size_t)n1 * D + lane] = __float2half_rn(h1);
            if (v2) hout[(size_t)n2 * D + lane] = __float2half_rn(h2);
            if (v3) hout[(size_t)n3 * D + lane] = __float2half_rn(h3);
        }
    }
}

// ---------------------------------------------------------------------------
// Final linear, NODE-UNROLL-4: out = h@Wlin + blin. Same amortization.
// ---------------------------------------------------------------------------
__global__ __launch_bounds__(256)
void final_mm_kernel(const float* __restrict__ h,
                     const float* __restrict__ W,
                     const float* __restrict__ bias,
                     float* __restrict__ out,
                     int n) {
    const int lane = threadIdx.x & 63;
    const int wave = threadIdx.x >> 6;
    const int gw = blockIdx.x * 4 + wave;
    const int nw = gridDim.x * 4;
    const float bv = bias[lane];

    for (int base = gw * 4; base < n; base += nw * 4) {
        const int n0 = base, n1 = base + 1, n2 = base + 2, n3 = base + 3;
        const bool v1 = n1 < n, v2 = n2 < n, v3 = n3 < n;

        const unsigned hu0 = __float_as_uint(h[(size_t)n0 * D + lane]);
        const unsigned hu1 = v1 ? __float_as_uint(h[(size_t)n1 * D + lane]) : 0u;
        const unsigned hu2 = v2 ? __float_as_uint(h[(size_t)n2 * D + lane]) : 0u;
        const unsigned hu3 = v3 ? __float_as_uint(h[(size_t)n3 * D + lane]) : 0u;

        float oA0 = bv, oB0 = 0.0f;
        float oA1 = bv, oB1 = 0.0f;
        float oA2 = bv, oB2 = 0.0f;
        float oA3 = bv, oB3 = 0.0f;

#pragma unroll
        for (int k = 0; k < D; k += 2) {
            const float w0 = W[(k + 0) * D + lane];
            const float w1 = W[(k + 1) * D + lane];
            oA0 = fmaf(rl(hu0, k), w0, oA0); oB0 = fmaf(rl(hu0, k + 1), w1, oB0);
            oA1 = fmaf(rl(hu1, k), w0, oA1); oB1 = fmaf(rl(hu1, k + 1), w1, oB1);
            oA2 = fmaf(rl(hu2, k), w0, oA2); oB2 = fmaf(rl(hu2, k + 1), w1, oB2);
            oA3 = fmaf(rl(hu3, k), w0, oA3); oB3 = fmaf(rl(hu3, k + 1), w1, oB3);
        }

        out[(size_t)n0 * D + lane] = oA0 + oB0;
        if (v1) out[(size_t)n1 * D + lane] = oA1 + oB1;
        if (v2) out[(size_t)n2 * D + lane] = oA2 + oB2;
        if (v3) out[(size_t)n3 * D + lane] = oA3 + oB3;
    }
}

extern "C" void kernel_launch(void* const* d_in, const int* in_sizes, int n_in,
                              void* d_out, int out_size, void* d_ws, size_t ws_size,
                              hipStream_t stream) {
    const float* x    = (const float*)d_in[0];
    const int*   ei   = (const int*)d_in[1];
    const float* W1l  = (const float*)d_in[2];
    const float* b1   = (const float*)d_in[3];
    const float* W1r  = (const float*)d_in[4];
    const float* W2l  = (const float*)d_in[5];
    const float* b2   = (const float*)d_in[6];
    const float* W2r  = (const float*)d_in[7];
    const float* Wlin = (const float*)d_in[8];
    const float* blin = (const float*)d_in[9];

    const int N_ = in_sizes[0] / D;      // 100000
    const int E_ = in_sizes[1] / 2;      // 1600000
    const int* src = ei;
    const int* dst = ei + E_;

    // workspace layout
    int* bcnt     = (int*)d_ws;                     // MAXBUCK
    int* bbase    = bcnt + MAXBUCK;                 // MAXBUCK+1
    int* cursor   = bbase + MAXBUCK + 1;            // MAXBUCK
    int* rowStart = cursor + MAXBUCK;               // N+1
    unsigned* pairs = (unsigned*)(rowStart + N_ + 1);// E (packed src<<7|dloc)
    int* csr      = (int*)(pairs + E_);             // E
    size_t iofs = (size_t)((csr + E_) - (int*)d_ws);
    iofs = (iofs + 3) & ~(size_t)3;                 // 16B-align float region
    float* mbuf   = (float*)d_ws + iofs;            // N*64 (aggregated mean)
    float* hbuf   = mbuf + (size_t)N_ * D;          // N*64 (h1, then h2 in place)
    // fp16 feature buffer: x-half for layer 1, then h1-half for layer 2
    __half* fh    = (__half*)(hbuf + (size_t)N_ * D); // N*64 halves (12.8 MB)

    const int nbuck = (N_ + BNODES - 1) >> BSHIFT;          // 782
    const int npart = (E_ + PA_EDGES - 1) / PA_EDGES;       // 391

    hipMemsetAsync(bcnt, 0, (size_t)MAXBUCK * sizeof(int), stream);

    bhist_kernel<<<npart, 256, 0, stream>>>(dst, bcnt, E_, nbuck);
    bucket_scan_kernel<<<1, 256, 0, stream>>>(bcnt, bbase, cursor, nbuck, E_);
    partition_kernel<<<npart, 256, 0, stream>>>(src, dst, cursor, pairs, E_, nbuck);
    bucket_fill_kernel<<<nbuck, 256, 0, stream>>>(pairs, bbase, rowStart, csr, N_, E_);
    cast_half_kernel<<<1024, 256, 0, stream>>>(x, fh, N_ * D / 2);

    // Layer 1: m1 = mean(xh[nbrs]) ; h1 = ELU(m1@W1l + b1 + x@W1r)  (+h1 fp16)
    aggmean_kernel<<<2048, 256, 0, stream>>>(fh, rowStart, csr, mbuf, N_);
    fused_mm_kernel<<<2048, 256, 0, stream>>>(mbuf, x, W1l, b1, W1r, hbuf, fh, N_);
    // Layer 2: m2 = mean(h1h[nbrs]) ; h2 = ELU(m2@W2l + b2 + h1@W2r)  (in place)
    aggmean_kernel<<<2048, 256, 0, stream>>>(fh, rowStart, csr, mbuf, N_);
    fused_mm_kernel<<<2048, 256, 0, stream>>>(mbuf, hbuf, W2l, b2, W2r, hbuf, nullptr, N_);
    // Final: out = h2@Wlin + blin
    final_mm_kernel<<<2048, 256, 0, stream>>>(hbuf, Wlin, blin, (float*)d_out, N_);
}

// Round 10
// 261.149 us; speedup vs baseline: 1.4276x; 1.4276x over previous
//
#include <hip/hip_runtime.h>
#include <hip/hip_fp16.h>
#include <cmath>

#define D 64
#define PA_EDGES 4096     // edges per partition/bhist block
#define BSHIFT 7          // bucket = 128 nodes
#define BNODES 128
#define MAXBUCK 1024      // supports N <= 131072
#define PB_CAP 4096       // LDS csr staging per bucket (avg 2048, ~45 sigma)

typedef _Float16 hh2 __attribute__((ext_vector_type(2)));

// f32-accumulating fp16 dot2: d = a.x*b.x + a.y*b.y + c  (one VALU op).
__device__ __forceinline__ float dot2(unsigned a, unsigned b, float c) {
#if __has_builtin(__builtin_amdgcn_fdot2)
    return __builtin_amdgcn_fdot2(__builtin_bit_cast(hh2, a),
                                  __builtin_bit_cast(hh2, b), c, false);
#else
    const __half2 ah = __builtin_bit_cast(__half2, a);
    const __half2 bh = __builtin_bit_cast(__half2, b);
    const float2 af = __half22float2(ah), bf = __half22float2(bh);
    return fmaf(af.x, bf.x, fmaf(af.y, bf.y, c));
#endif
}

__device__ __forceinline__ unsigned rlu(unsigned v, int k) {
    return (unsigned)__builtin_amdgcn_readlane((int)v, k);
}

// ---------------------------------------------------------------------------
// Per-BUCKET histogram, LDS-privatized.
// ---------------------------------------------------------------------------
__global__ __launch_bounds__(256)
void bhist_kernel(const int* __restrict__ dst, int* __restrict__ bcnt, int E, int nbuck) {
    __shared__ int lh[MAXBUCK];
    const int t = threadIdx.x;
    const int e0 = blockIdx.x * PA_EDGES;
    const int ecnt = min(PA_EDGES, E - e0);
    for (int i = t; i < MAXBUCK; i += 256) lh[i] = 0;
    __syncthreads();
    for (int i = t; i < ecnt; i += 256) atomicAdd(&lh[dst[e0 + i] >> BSHIFT], 1);
    __syncthreads();
    for (int b = t; b < nbuck; b += 256) {
        const int c = lh[b];
        if (c) atomicAdd(&bcnt[b], c);
    }
}

// ---------------------------------------------------------------------------
// Exclusive scan of bucket counts -> bbase (and cursor copy). One block.
// ---------------------------------------------------------------------------
__global__ __launch_bounds__(256)
void bucket_scan_kernel(const int* __restrict__ bcnt, int* __restrict__ bbase,
                        int* __restrict__ cursor, int nbuck, int E) {
    __shared__ int red[256];
    const int t = threadIdx.x;
    const int c0 = (4 * t + 0 < nbuck) ? bcnt[4 * t + 0] : 0;
    const int c1 = (4 * t + 1 < nbuck) ? bcnt[4 * t + 1] : 0;
    const int c2 = (4 * t + 2 < nbuck) ? bcnt[4 * t + 2] : 0;
    const int c3 = (4 * t + 3 < nbuck) ? bcnt[4 * t + 3] : 0;
    red[t] = c0 + c1 + c2 + c3;
    __syncthreads();
    for (int off = 1; off < 256; off <<= 1) {
        int u = (t >= off) ? red[t - off] : 0;
        __syncthreads();
        red[t] += u;
        __syncthreads();
    }
    const int excl = (t == 0) ? 0 : red[t - 1];
    const int e0 = excl, e1 = excl + c0, e2 = excl + c0 + c1, e3 = excl + c0 + c1 + c2;
    if (4 * t + 0 <= nbuck) { bbase[4 * t + 0] = e0; }
    if (4 * t + 1 <= nbuck) { bbase[4 * t + 1] = e1; }
    if (4 * t + 2 <= nbuck) { bbase[4 * t + 2] = e2; }
    if (4 * t + 3 <= nbuck) { bbase[4 * t + 3] = e3; }
    if (4 * t + 0 < nbuck) cursor[4 * t + 0] = e0;
    if (4 * t + 1 < nbuck) cursor[4 * t + 1] = e1;
    if (4 * t + 2 < nbuck) cursor[4 * t + 2] = e2;
    if (4 * t + 3 < nbuck) cursor[4 * t + 3] = e3;
    if (t == 255) bbase[nbuck] = E;   // total (exclusive scan end)
}

// ---------------------------------------------------------------------------
// Bucket partition: (src, dst) -> packed 32-bit (src<<7 | dst&127), grouped
// by bucket (dst>>7) in `pairs`. LDS-staged; int LDS atomics only (native
// ds_add_u32 -- float LDS atomics are CAS loops on HIP, never use them).
// ---------------------------------------------------------------------------
__global__ __launch_bounds__(256)
void partition_kernel(const int* __restrict__ src, const int* __restrict__ dst,
                      int* __restrict__ cursor, unsigned* __restrict__ pairs,
                      int E, int nbuck) {
    __shared__ int lhist[MAXBUCK];            // counts, then local fill cursors
    __shared__ int lbase[MAXBUCK];            // local exclusive scan
    __shared__ int gbase[MAXBUCK];            // reserved global positions
    __shared__ int red[256];
    __shared__ unsigned stage[PA_EDGES];      // 16 KB
    __shared__ unsigned short sbuck[PA_EDGES];// 8 KB bucket id per staged slot

    const int t = threadIdx.x;
    const int e0 = blockIdx.x * PA_EDGES;
    const int ecnt = min(PA_EDGES, E - e0);

    for (int i = t; i < MAXBUCK; i += 256) lhist[i] = 0;
    __syncthreads();
    for (int i = t; i < ecnt; i += 256) atomicAdd(&lhist[dst[e0 + i] >> BSHIFT], 1);
    __syncthreads();

    // exclusive scan over 1024 entries: each thread owns 4 consecutive slots
    const int c0 = lhist[4 * t], c1 = lhist[4 * t + 1];
    const int c2 = lhist[4 * t + 2], c3 = lhist[4 * t + 3];
    red[t] = c0 + c1 + c2 + c3;
    __syncthreads();
    for (int off = 1; off < 256; off <<= 1) {
        int u = (t >= off) ? red[t - off] : 0;
        __syncthreads();
        red[t] += u;
        __syncthreads();
    }
    const int excl = (t == 0) ? 0 : red[t - 1];
    lbase[4 * t]     = excl;
    lbase[4 * t + 1] = excl + c0;
    lbase[4 * t + 2] = excl + c0 + c1;
    lbase[4 * t + 3] = excl + c0 + c1 + c2;
    for (int b = t; b < nbuck; b += 256) {
        const int c = lhist[b];
        gbase[b] = c ? atomicAdd(&cursor[b], c) : 0;
    }
    __syncthreads();
    for (int i = t; i < MAXBUCK; i += 256) lhist[i] = 0;   // reuse as fill cursors
    __syncthreads();
    for (int i = t; i < ecnt; i += 256) {
        const int d = dst[e0 + i];
        const int b = d >> BSHIFT;
        const int p = lbase[b] + atomicAdd(&lhist[b], 1);
        stage[p] = ((unsigned)src[e0 + i] << BSHIFT) | (unsigned)(d & (BNODES - 1));
        sbuck[p] = (unsigned short)b;
    }
    __syncthreads();
    for (int i = t; i < ecnt; i += 256) {
        const int b = sbuck[i];
        pairs[gbase[b] + (i - lbase[b])] = stage[i];
    }
}

// ---------------------------------------------------------------------------
// Bucket CSR fill + per-node rowStart derivation, fully on-chip.
// ---------------------------------------------------------------------------
__global__ __launch_bounds__(256)
void bucket_fill_kernel(const unsigned* __restrict__ pairs, const int* __restrict__ bbase,
                        int* __restrict__ rowStart, int* __restrict__ csr, int n, int E) {
    __shared__ int lcsr[PB_CAP];          // 16 KB
    __shared__ int lcnt[BNODES];          // per-node degree
    __shared__ int lrs[BNODES];           // per-node row start (bucket-relative)
    __shared__ int s[BNODES];             // scan workspace
    __shared__ int lfill[BNODES];
    const int t = threadIdx.x;
    const int node0 = blockIdx.x << BSHIFT;
    const int bn = min(BNODES, n - node0);
    const int base = bbase[blockIdx.x];
    const int cntE = bbase[blockIdx.x + 1] - base;

    if (t < BNODES) { lcnt[t] = 0; lfill[t] = 0; }
    __syncthreads();
    for (int i = t; i < cntE; i += 256)
        atomicAdd(&lcnt[pairs[base + i] & (BNODES - 1)], 1);
    __syncthreads();
    if (t < BNODES) s[t] = lcnt[t];
    __syncthreads();
    for (int off = 1; off < BNODES; off <<= 1) {
        int u = (t >= off && t < BNODES) ? s[t - off] : 0;
        __syncthreads();
        if (t < BNODES) s[t] += u;
        __syncthreads();
    }
    if (t < BNODES) lrs[t] = (t == 0) ? 0 : s[t - 1];
    __syncthreads();
    if (t < bn) rowStart[node0 + t] = base + lrs[t];
    if (blockIdx.x == gridDim.x - 1 && t == 0) rowStart[n] = E;

    if (cntE <= PB_CAP) {
        for (int i = t; i < cntE; i += 256) {
            const unsigned pr = pairs[base + i];
            const int dl = (int)(pr & (BNODES - 1));
            const int p = lrs[dl] + atomicAdd(&lfill[dl], 1);
            lcsr[p] = (int)(pr >> BSHIFT);
        }
        __syncthreads();
        for (int i = t; i < cntE; i += 256) csr[base + i] = lcsr[i];
    } else {   // safety fallback (statistically unreachable for random dst)
        for (int i = t; i < cntE; i += 256) {
            const unsigned pr = pairs[base + i];
            const int dl = (int)(pr & (BNODES - 1));
            const int p = base + lrs[dl] + atomicAdd(&lfill[dl], 1);
            csr[p] = (int)(pr >> BSHIFT);
        }
    }
}

// ---------------------------------------------------------------------------
// f32 -> f16 cast (vectorized, grid-stride). Dword i of a row holds halves
// (2i, 2i+1) -- the packing every fp16 consumer below assumes.
// ---------------------------------------------------------------------------
__global__ __launch_bounds__(256)
void cast_half_kernel(const float* __restrict__ in, __half* __restrict__ out, int n2) {
    const float2* in2 = (const float2*)in;
    __half2* out2 = (__half2*)out;
    int i = blockIdx.x * 256 + threadIdx.x;
    const int st = gridDim.x * 256;
    for (; i < n2; i += st) {
        const float2 v = in2[i];
        out2[i] = __floats2half2_rn(v.x, v.y);
    }
}

// ---------------------------------------------------------------------------
// Pack the 5 weight matrices to half2 k-pairs: wp[mat][p*64+j] =
// (W[2p][j], W[2p+1][j]) so dot2 with a broadcast input dword (2 k-values)
// consumes 2 MACs per instruction.
// ---------------------------------------------------------------------------
__global__ __launch_bounds__(256)
void pack_w_kernel(const float* __restrict__ W1l, const float* __restrict__ W1r,
                   const float* __restrict__ W2l, const float* __restrict__ W2r,
                   const float* __restrict__ Wlin, unsigned* __restrict__ wp) {
    const int t = blockIdx.x * 256 + threadIdx.x;
    if (t >= 5 * 2048) return;
    const float* W = (t < 2048) ? W1l : (t < 4096) ? W1r : (t < 6144) ? W2l
                    : (t < 8192) ? W2r : Wlin;
    const int idx = t & 2047;
    const int p = idx >> 6, j = idx & 63;
    const __half2 h = __floats2half2_rn(W[(2 * p) * D + j], W[(2 * p + 1) * D + j]);
    wp[t] = __builtin_bit_cast(unsigned, h);
}

// ---------------------------------------------------------------------------
// Gather-mean from the fp16 feature copy; OUTPUT NOW PACKED fp16 (halves the
// write traffic; downstream transforms consume fp16 anyway).
// ---------------------------------------------------------------------------
__device__ __forceinline__ void addh4(float4& a, const __half* __restrict__ p) {
    union { unsigned long long u; __half2 h[2]; } r;
    r.u = *(const unsigned long long*)p;       // 8 B load
    const float2 f0 = __half22float2(r.h[0]);
    const float2 f1 = __half22float2(r.h[1]);
    a.x += f0.x; a.y += f0.y; a.z += f1.x; a.w += f1.y;
}

__global__ __launch_bounds__(256)
void aggmean_kernel(const __half* __restrict__ xh, const int* __restrict__ rowStart,
                    const int* __restrict__ csr, __half* __restrict__ m, int n) {
    const int lane = threadIdx.x & 63;
    const int g = lane >> 4;              // group 0..3
    const int gl = lane & 15;             // lane in group
    const int wave = threadIdx.x >> 6;
    const int gw = blockIdx.x * 4 + wave;
    const int nw = gridDim.x * 4;

    for (int node = gw; node < n; node += nw) {
        const int r0 = rowStart[node];
        const int r1 = rowStart[node + 1];
        float4 acc0 = make_float4(0.f, 0.f, 0.f, 0.f);
        float4 acc1 = make_float4(0.f, 0.f, 0.f, 0.f);

        int j = r0;
        for (; j + 16 <= r1; j += 16) {
            const int i0 = csr[j + 0  + g];
            const int i1 = csr[j + 4  + g];
            const int i2 = csr[j + 8  + g];
            const int i3 = csr[j + 12 + g];
            addh4(acc0, &xh[(size_t)i0 * D + gl * 4]);
            addh4(acc1, &xh[(size_t)i1 * D + gl * 4]);
            addh4(acc0, &xh[(size_t)i2 * D + gl * 4]);
            addh4(acc1, &xh[(size_t)i3 * D + gl * 4]);
        }
        const int rem = r1 - j;
        if (rem > 0) {
            if (0 + g < rem) {
                const int sidx = csr[j + 0 + g];
                addh4(acc0, &xh[(size_t)sidx * D + gl * 4]);
            }
            if (4 + g < rem) {
                const int sidx = csr[j + 4 + g];
                addh4(acc1, &xh[(size_t)sidx * D + gl * 4]);
            }
            if (8 + g < rem) {
                const int sidx = csr[j + 8 + g];
                addh4(acc0, &xh[(size_t)sidx * D + gl * 4]);
            }
            if (12 + g < rem) {
                const int sidx = csr[j + 12 + g];
                addh4(acc1, &xh[(size_t)sidx * D + gl * 4]);
            }
        }

        float4 a;
        a.x = acc0.x + acc1.x; a.y = acc0.y + acc1.y;
        a.z = acc0.z + acc1.z; a.w = acc0.w + acc1.w;
        a.x += __shfl_xor(a.x, 16); a.y += __shfl_xor(a.y, 16);
        a.z += __shfl_xor(a.z, 16); a.w += __shfl_xor(a.w, 16);
        a.x += __shfl_xor(a.x, 32); a.y += __shfl_xor(a.y, 32);
        a.z += __shfl_xor(a.z, 32); a.w += __shfl_xor(a.w, 32);

        if (lane < 16) {
            const float rdeg = 1.0f / fmaxf((float)(r1 - r0), 1.0f);
            const __half2 p0 = __floats2half2_rn(a.x * rdeg, a.y * rdeg);
            const __half2 p1 = __floats2half2_rn(a.z * rdeg, a.w * rdeg);
            uint2 o = make_uint2(__builtin_bit_cast(unsigned, p0),
                                 __builtin_bit_cast(unsigned, p1));
            ((uint2*)m)[(size_t)node * 16 + gl] = o;
        }
    }
}

// ---------------------------------------------------------------------------
// Fused SAGE transform (fp16 dot2): h = ELU(m@Wa + ba + res@Wb), all inputs
// packed fp16, f32 accumulate. Per node: 64 readlane + 64 dot2 + 64 weight
// dword loads -- roughly HALF the VALU and HALF the VMEM of the f32 readlane
// +fma version (54 us, R6). Output written packed fp16 IN PLACE of the f32
// buffer (residual/gather/final all consume fp16). In-place res==hout safe:
// each node reads its own row before writing it.
// ---------------------------------------------------------------------------
__global__ __launch_bounds__(256)
void fused_mm_kernel(const __half* __restrict__ m,
                     const __half* __restrict__ res,
                     const unsigned* __restrict__ WpA,
                     const float* __restrict__ ba,
                     const unsigned* __restrict__ WpB,
                     __half* __restrict__ hout,
                     int n) {
    const int lane = threadIdx.x & 63;
    const int wave = threadIdx.x >> 6;
    const int gw = blockIdx.x * 4 + wave;
    const int nw = gridDim.x * 4;
    const float bva = ba[lane];

    for (int node = gw; node < n; node += nw) {
        const unsigned mu = ((const unsigned*)m)[(size_t)node * 32 + (lane & 31)];
        const unsigned ru = ((const unsigned*)res)[(size_t)node * 32 + (lane & 31)];
        float o0 = bva, o1 = 0.0f, o2 = 0.0f, o3 = 0.0f;
#pragma unroll
        for (int p = 0; p < 32; p += 4) {
            o0 = dot2(rlu(mu, p + 0), WpA[(p + 0) * D + lane], o0);
            o0 = dot2(rlu(ru, p + 0), WpB[(p + 0) * D + lane], o0);
            o1 = dot2(rlu(mu, p + 1), WpA[(p + 1) * D + lane], o1);
            o1 = dot2(rlu(ru, p + 1), WpB[(p + 1) * D + lane], o1);
            o2 = dot2(rlu(mu, p + 2), WpA[(p + 2) * D + lane], o2);
            o2 = dot2(rlu(ru, p + 2), WpB[(p + 2) * D + lane], o2);
            o3 = dot2(rlu(mu, p + 3), WpA[(p + 3) * D + lane], o3);
            o3 = dot2(rlu(ru, p + 3), WpB[(p + 3) * D + lane], o3);
        }
        float h = (o0 + o1) + (o2 + o3);
        h = h > 0.0f ? h : expm1f(h);   // ELU(alpha=1)
        const float hp = __shfl_xor(h, 1);
        if (!(lane & 1)) {
            const __half2 ph = __floats2half2_rn(h, hp);
            ((unsigned*)hout)[(size_t)node * 32 + (lane >> 1)] =
                __builtin_bit_cast(unsigned, ph);
        }
    }
}

// ---------------------------------------------------------------------------
// Final linear (fp16 dot2): out = h@Wlin + blin, f32 output.
// ---------------------------------------------------------------------------
__global__ __launch_bounds__(256)
void final_mm_kernel(const __half* __restrict__ h,
                     const unsigned* __restrict__ Wp,
                     const float* __restrict__ bias,
                     float* __restrict__ out,
                     int n) {
    const int lane = threadIdx.x & 63;
    const int wave = threadIdx.x >> 6;
    const int gw = blockIdx.x * 4 + wave;
    const int nw = gridDim.x * 4;
    const float bv = bias[lane];

    for (int node = gw; node < n; node += nw) {
        const unsigned hu = ((const unsigned*)h)[(size_t)node * 32 + (lane & 31)];
        float o0 = bv, o1 = 0.0f, o2 = 0.0f, o3 = 0.0f;
#pragma unroll
        for (int p = 0; p < 32; p += 4) {
            o0 = dot2(rlu(hu, p + 0), Wp[(p + 0) * D + lane], o0);
            o1 = dot2(rlu(hu, p + 1), Wp[(p + 1) * D + lane], o1);
            o2 = dot2(rlu(hu, p + 2), Wp[(p + 2) * D + lane], o2);
            o3 = dot2(rlu(hu, p + 3), Wp[(p + 3) * D + lane], o3);
        }
        out[(size_t)node * D + lane] = (o0 + o1) + (o2 + o3);
    }
}

extern "C" void kernel_launch(void* const* d_in, const int* in_sizes, int n_in,
                              void* d_out, int out_size, void* d_ws, size_t ws_size,
                              hipStream_t stream) {
    const float* x    = (const float*)d_in[0];
    const int*   ei   = (const int*)d_in[1];
    const float* W1l  = (const float*)d_in[2];
    const float* b1   = (const float*)d_in[3];
    const float* W1r  = (const float*)d_in[4];
    const float* W2l  = (const float*)d_in[5];
    const float* b2   = (const float*)d_in[6];
    const float* W2r  = (const float*)d_in[7];
    const float* Wlin = (const float*)d_in[8];
    const float* blin = (const float*)d_in[9];

    const int N_ = in_sizes[0] / D;      // 100000
    const int E_ = in_sizes[1] / 2;      // 1600000
    const int* src = ei;
    const int* dst = ei + E_;

    // workspace layout
    int* bcnt     = (int*)d_ws;                     // MAXBUCK
    int* bbase    = bcnt + MAXBUCK;                 // MAXBUCK+1
    int* cursor   = bbase + MAXBUCK + 1;            // MAXBUCK
    int* rowStart = cursor + MAXBUCK;               // N+1
    unsigned* pairs = (unsigned*)(rowStart + N_ + 1);// E (packed src<<7|dloc)
    int* csr      = (int*)(pairs + E_);             // E
    unsigned* wp  = (unsigned*)(csr + E_);          // 5*2048 packed weights
    __half* mh    = (__half*)(wp + 5 * 2048);       // N*64 halves (mean, packed)
    __half* fh    = mh + (size_t)N_ * D;            // N*64 halves (x -> h1 -> h2)

    const unsigned* wp1l  = wp;
    const unsigned* wp1r  = wp + 2048;
    const unsigned* wp2l  = wp + 4096;
    const unsigned* wp2r  = wp + 6144;
    const unsigned* wplin = wp + 8192;

    const int nbuck = (N_ + BNODES - 1) >> BSHIFT;          // 782
    const int npart = (E_ + PA_EDGES - 1) / PA_EDGES;       // 391

    hipMemsetAsync(bcnt, 0, (size_t)MAXBUCK * sizeof(int), stream);

    bhist_kernel<<<npart, 256, 0, stream>>>(dst, bcnt, E_, nbuck);
    bucket_scan_kernel<<<1, 256, 0, stream>>>(bcnt, bbase, cursor, nbuck, E_);
    partition_kernel<<<npart, 256, 0, stream>>>(src, dst, cursor, pairs, E_, nbuck);
    bucket_fill_kernel<<<nbuck, 256, 0, stream>>>(pairs, bbase, rowStart, csr, N_, E_);
    cast_half_kernel<<<1024, 256, 0, stream>>>(x, fh, N_ * D / 2);
    pack_w_kernel<<<40, 256, 0, stream>>>(W1l, W1r, W2l, W2r, Wlin, wp);

    // Layer 1: m1 = mean(xh[nbrs]) ; h1 = ELU(m1@W1l + b1 + x@W1r)  -> fh (fp16)
    aggmean_kernel<<<2048, 256, 0, stream>>>(fh, rowStart, csr, mh, N_);
    fused_mm_kernel<<<2048, 256, 0, stream>>>(mh, fh, wp1l, b1, wp1r, fh, N_);
    // Layer 2: m2 = mean(h1[nbrs]) ; h2 = ELU(m2@W2l + b2 + h1@W2r)  -> fh (fp16)
    aggmean_kernel<<<2048, 256, 0, stream>>>(fh, rowStart, csr, mh, N_);
    fused_mm_kernel<<<2048, 256, 0, stream>>>(mh, fh, wp2l, b2, wp2r, fh, N_);
    // Final: out = h2@Wlin + blin  (f32)
    final_mm_kernel<<<2048, 256, 0, stream>>>(fh, wplin, blin, (float*)d_out, N_);
}